// Round 1
// baseline (177.601 us; speedup 1.0000x reference)
//
#include <hip/hip_runtime.h>

#define B_ 512
#define C_ 64
#define H_ 128
#define P_ 16
#define G_ 2
#define EPS 1e-5f

// LDS row strides (bf16 units) chosen for bank behavior + 16B frag alignment
#define XS_S 130   // xs_bf [C][XS_S]: bank (c + h/2)%32 -> 2-way on column reads
#define HB_S 136   // xp/hat [P][HB_S]: 272B rows, 16B-aligned frags
#define MB_S 72    // m_bf [P][MB_S]

#define MAGIC 0x9E3779B1u

typedef __attribute__((ext_vector_type(8))) short bf16x8;
typedef __attribute__((ext_vector_type(4))) float f32x4;

__device__ __forceinline__ unsigned short f2bf(float f) {  // round-nearest-even
    union { float f; unsigned u; } v; v.f = f;
    return (unsigned short)((v.u + 0x7FFFu + ((v.u >> 16) & 1u)) >> 16);
}
__device__ __forceinline__ float bf2f(unsigned short h) {
    union { unsigned u; float f; } v; v.u = ((unsigned)h) << 16; return v.f;
}
// cheap round (ties-away) for the phase-E-only x staging: 2 ops per value
__device__ __forceinline__ unsigned packbf_fast(float lo, float hi) {
    union { float f; unsigned u; } a, b; a.f = lo; b.f = hi;
    return ((a.u + 0x8000u) >> 16) | (((b.u + 0x8000u) >> 16) << 16);
}
// split two floats into packed hi-pair and lo-pair (double-bf16, RNE)
__device__ __forceinline__ void split2(float a, float b, unsigned& hi, unsigned& lo) {
    const unsigned short ah = f2bf(a), bh = f2bf(b);
    const unsigned short al = f2bf(a - bf2f(ah)), bl = f2bf(b - bf2f(bh));
    hi = (unsigned)ah | ((unsigned)bh << 16);
    lo = (unsigned)al | ((unsigned)bl << 16);
}
// relu on 8 packed bf16: zero each half whose sign bit is set
__device__ __forceinline__ bf16x8 relu8(bf16x8 x) {
    union { bf16x8 v; unsigned u[4]; } a; a.v = x;
    #pragma unroll
    for (int i = 0; i < 4; ++i) {
        unsigned s = a.u[i] & 0x80008000u;
        a.u[i] &= ~((s >> 15) * 0xFFFFu);
    }
    return a.v;
}

// Single fused kernel. grid=512 == guaranteed capacity (2 blocks/CU * 256 CU via
// __launch_bounds__(256,2), LDS 40.8KB <= 80KB) -> all blocks co-resident, so the
// flag handshake below cannot deadlock regardless of dispatch order.
__global__ __launch_bounds__(256, 2) void fused_kernel(
    const float* __restrict__ x,          // [B,C,H]
    const float* __restrict__ x_prompt,   // [B,P,H]
    const float* __restrict__ emb_column, // [C,H]
    const float* __restrict__ emb_prompt, // [P,H]
    const float* __restrict__ lin_w,      // [H,2H]
    const float* __restrict__ lin_b,      // [H]
    const float* __restrict__ ln_col_w, const float* __restrict__ ln_col_b,
    const float* __restrict__ ln_pr_w,  const float* __restrict__ ln_pr_b,
    const float* __restrict__ expand_w,   // [P]
    const float* __restrict__ gn_w, const float* __restrict__ gn_b,  // [P]
    float* __restrict__ hat0,             // ws: [P,H] = ep@W1^T + lin_b + ep
    unsigned short* __restrict__ ec_hi,   // ws: [C,H]
    unsigned short* __restrict__ ec_lo,   // ws: [C,H]
    unsigned short* __restrict__ w2_hi,   // ws: [H,H], [h][k]=lin_w[h][H+k]
    unsigned short* __restrict__ w2_lo,   // ws: [H,H]
    unsigned* __restrict__ flags,         // ws: [64] writer-ready flags
    float* __restrict__ out)              // [B,P,H]
{
    __shared__ __align__(16) unsigned short xs_bf[C_ * XS_S];    // 16640 B
    __shared__ __align__(16) unsigned short xp_hi[P_ * HB_S];    // 4352 B
    __shared__ __align__(16) unsigned short xp_lo[P_ * HB_S];    // 4352 B
    __shared__ __align__(16) unsigned short hat_hi[P_ * HB_S];   // 4352 B
    __shared__ __align__(16) unsigned short hat_lo[P_ * HB_S];   // 4352 B
    __shared__ __align__(16) float sm[P_ * C_];                  // 4096 B (doubles as ep_row for writer blocks 48..63)
    __shared__ __align__(16) unsigned short m_bf[P_ * MB_S];     // 2304 B
    __shared__ float red[16];
    __shared__ float stat[4];   // Xsum, Xsq, R1=sum relu(x), R2=sum relu(x)^2
    __shared__ float s1_s[P_], s2_s[P_];
    __shared__ float cA[P_], cB[P_], cD[P_];

    const int t = threadIdx.x;
    const int b = blockIdx.x;
    const int lane = t & 63;
    const int w = t >> 6;       // wave id 0..3
    const int nl = lane & 15;   // MFMA n/m lane coord
    const int quad = lane >> 4; // MFMA quad

    // prefetch phase-B epilogue xp operand (latency overlaps staging/prep)
    float xpr[2][4];
    {
        const float* xpg = x_prompt + (size_t)b * (P_ * H_);
        #pragma unroll
        for (int T = 0; T < 2; ++T) {
            const int h = w * 32 + T * 16 + nl;
            #pragma unroll
            for (int r = 0; r < 4; ++r)
                xpr[T][r] = xpg[(quad * 4 + r) * H_ + h];
        }
    }

    // ---- distributed prep: first 64 blocks do a slice, then release a flag ----
    if (b < 64) {
        if (b < 32) {
            // w2 hi/lo split: 512 elements per block, 2 per thread
            const int f = b * 512 + t * 2;
            const int h = f >> 7, k = f & 127;
            const float2 q = *(const float2*)(lin_w + h * (2 * H_) + H_ + k);
            unsigned hi, lo;
            split2(q.x, q.y, hi, lo);
            *(unsigned*)(w2_hi + f) = hi;
            *(unsigned*)(w2_lo + f) = lo;
        } else if (b < 48) {
            // ec layernorm -> hi/lo: one row per wave
            const int r = (b - 32) * 4 + w;
            const float v0 = emb_column[r * H_ + lane];
            const float v1 = emb_column[r * H_ + lane + 64];
            float s = v0 + v1, s2 = v0 * v0 + v1 * v1;
            #pragma unroll
            for (int m = 1; m < 64; m <<= 1) { s += __shfl_xor(s, m, 64); s2 += __shfl_xor(s2, m, 64); }
            const float mean = s * (1.f / H_);
            const float rs = rsqrtf(s2 * (1.f / H_) - mean * mean + EPS);
            const float a0 = (v0 - mean) * rs * ln_col_w[lane]      + ln_col_b[lane];
            const float a1 = (v1 - mean) * rs * ln_col_w[lane + 64] + ln_col_b[lane + 64];
            const unsigned short h0 = f2bf(a0), h1 = f2bf(a1);
            ec_hi[r * H_ + lane]      = h0;
            ec_hi[r * H_ + lane + 64] = h1;
            ec_lo[r * H_ + lane]      = f2bf(a0 - bf2f(h0));
            ec_lo[r * H_ + lane + 64] = f2bf(a1 - bf2f(h1));
        } else {
            // ep layernorm (row p) + hat0 row p = ep@W1^T + lin_b + ep
            float* ep_row = sm;  // reuse sm (untouched until phase C)
            const int p = b - 48;
            const float v0 = emb_prompt[p * H_ + lane];
            const float v1 = emb_prompt[p * H_ + lane + 64];
            float s = v0 + v1, s2 = v0 * v0 + v1 * v1;
            #pragma unroll
            for (int m = 1; m < 64; m <<= 1) { s += __shfl_xor(s, m, 64); s2 += __shfl_xor(s2, m, 64); }
            const float mean = s * (1.f / H_);
            const float rs = rsqrtf(s2 * (1.f / H_) - mean * mean + EPS);
            if (w == 0) {
                ep_row[lane]      = (v0 - mean) * rs * ln_pr_w[lane]      + ln_pr_b[lane];
                ep_row[lane + 64] = (v1 - mean) * rs * ln_pr_w[lane + 64] + ln_pr_b[lane + 64];
            }
            __syncthreads();
            const int h = t >> 1;
            const int kh = (t & 1) * 16;  // float4 units
            const float4* w1 = (const float4*)(lin_w + h * (2 * H_)) + kh;
            const float4* e4 = (const float4*)ep_row + kh;
            float acc = 0.f;
            #pragma unroll
            for (int k = 0; k < 16; ++k) {
                const float4 W = w1[k], E = e4[k];
                acc += E.x * W.x + E.y * W.y + E.z * W.z + E.w * W.w;
            }
            acc += __shfl_xor(acc, 1, 64);
            if ((t & 1) == 0) hat0[p * H_ + h] = acc + lin_b[h] + ep_row[h];
        }
        // all block stores drained (syncthreads waits vmcnt(0)), then release flag
        __syncthreads();
        if (t == 0)
            __hip_atomic_store(&flags[b], MAGIC, __ATOMIC_RELEASE, __HIP_MEMORY_SCOPE_AGENT);
    }

    // ---- phase A: x[b] -> bf16 LDS + stats; x_prompt[b] -> hi/lo LDS ----
    {
        const float4* x4 = (const float4*)(x + (size_t)b * (C_ * H_));
        float xsum = 0.f, xsq = 0.f, r1 = 0.f, r2 = 0.f;
        #pragma unroll
        for (int i = 0; i < 8; ++i) {
            const int idx = t + 256 * i;
            const float4 v = x4[idx];
            const int c = idx >> 5;
            const int h0 = (idx & 31) * 4;
            unsigned* dst = (unsigned*)(xs_bf + c * XS_S + h0);
            dst[0] = packbf_fast(v.x, v.y);
            dst[1] = packbf_fast(v.z, v.w);
            xsum += (v.x + v.y) + (v.z + v.w);
            xsq  += (v.x * v.x + v.y * v.y) + (v.z * v.z + v.w * v.w);
            const float rx = fmaxf(v.x, 0.f), ry = fmaxf(v.y, 0.f);
            const float rz = fmaxf(v.z, 0.f), rw = fmaxf(v.w, 0.f);
            r1 += (rx + ry) + (rz + rw);
            r2 += (rx * rx + ry * ry) + (rz * rz + rw * rw);
        }
        #pragma unroll
        for (int m = 1; m < 64; m <<= 1) {
            xsum += __shfl_xor(xsum, m, 64);
            xsq  += __shfl_xor(xsq,  m, 64);
            r1   += __shfl_xor(r1,   m, 64);
            r2   += __shfl_xor(r2,   m, 64);
        }
        if (lane == 0) {
            red[w * 4 + 0] = xsum; red[w * 4 + 1] = xsq;
            red[w * 4 + 2] = r1;   red[w * 4 + 3] = r2;
        }
        // xp -> hi/lo LDS: 8 consecutive values per thread
        const float4* xp4 = (const float4*)(x_prompt + (size_t)b * (P_ * H_));
        const float4 a0 = xp4[2 * t], a1 = xp4[2 * t + 1];
        const int p = t >> 4, hh = (t & 15) * 8;
        uint4 ph, pl;
        split2(a0.x, a0.y, ph.x, pl.x);
        split2(a0.z, a0.w, ph.y, pl.y);
        split2(a1.x, a1.y, ph.z, pl.z);
        split2(a1.z, a1.w, ph.w, pl.w);
        *(uint4*)(xp_hi + p * HB_S + hh) = ph;
        *(uint4*)(xp_lo + p * HB_S + hh) = pl;
    }
    __syncthreads();
    if (t < 4) stat[t] = red[t] + red[4 + t] + red[8 + t] + red[12 + t];

    // ---- wait for all 64 prep writers (each wave polls independently) ----
    {
        while (true) {
            const unsigned v = __hip_atomic_load(&flags[lane], __ATOMIC_ACQUIRE,
                                                 __HIP_MEMORY_SCOPE_AGENT);
            if (__ballot(v == MAGIC) == 0xFFFFFFFFFFFFFFFFull) break;
            __builtin_amdgcn_s_sleep(1);
        }
    }

    // ---- phase B (MFMA, hi/lo): hat = xp@W2^T + hat0 + xp ; store hi/lo ----
    {
        // hat0 loads issued first; latency hides under LDS reads + MFMA below
        float h0r[2][4];
        #pragma unroll
        for (int T = 0; T < 2; ++T) {
            const int h = w * 32 + T * 16 + nl;
            #pragma unroll
            for (int r = 0; r < 4; ++r)
                h0r[T][r] = hat0[(quad * 4 + r) * H_ + h];
        }
        f32x4 acc[2] = {{0.f,0.f,0.f,0.f},{0.f,0.f,0.f,0.f}};
        #pragma unroll
        for (int kk = 0; kk < 4; ++kk) {
            const bf16x8 a_hi = *(const bf16x8*)(xp_hi + nl * HB_S + kk * 32 + quad * 8);
            const bf16x8 a_lo = *(const bf16x8*)(xp_lo + nl * HB_S + kk * 32 + quad * 8);
            #pragma unroll
            for (int T = 0; T < 2; ++T) {
                const int h = w * 32 + T * 16 + nl;
                const bf16x8 b_hi = *(const bf16x8*)(w2_hi + h * H_ + kk * 32 + quad * 8);
                const bf16x8 b_lo = *(const bf16x8*)(w2_lo + h * H_ + kk * 32 + quad * 8);
                acc[T] = __builtin_amdgcn_mfma_f32_16x16x32_bf16(a_hi, b_hi, acc[T], 0, 0, 0);
                acc[T] = __builtin_amdgcn_mfma_f32_16x16x32_bf16(a_lo, b_hi, acc[T], 0, 0, 0);
                acc[T] = __builtin_amdgcn_mfma_f32_16x16x32_bf16(a_hi, b_lo, acc[T], 0, 0, 0);
            }
        }
        #pragma unroll
        for (int T = 0; T < 2; ++T) {
            const int h = w * 32 + T * 16 + nl;
            #pragma unroll
            for (int r = 0; r < 4; ++r) {
                const int p = quad * 4 + r;
                const float val = acc[T][r] + h0r[T][r] + xpr[T][r];
                const unsigned short hi = f2bf(val);
                hat_hi[p * HB_S + h] = hi;
                hat_lo[p * HB_S + h] = f2bf(val - bf2f(hi));
            }
        }
    }
    __syncthreads();

    // ---- group-norm per-p partial sums (uses stat) ----
    if (t < P_) {
        const float ew = expand_w[t];
        const float Ap = fabsf(ew);
        const float Bp = fminf(ew, 0.f);
        s1_s[t] = Ap * stat[2] + Bp * stat[0];
        s2_s[t] = ew * ew * (ew >= 0.f ? stat[3] : (stat[1] - stat[3]));
    }
    // ---- phase C (MFMA, hi/lo): scores[p][c] = hat @ ec^T ----
    {
        f32x4 acc = {0.f, 0.f, 0.f, 0.f};
        const int c = w * 16 + nl;
        #pragma unroll
        for (int kk = 0; kk < 4; ++kk) {
            const bf16x8 a_hi = *(const bf16x8*)(hat_hi + nl * HB_S + kk * 32 + quad * 8);
            const bf16x8 a_lo = *(const bf16x8*)(hat_lo + nl * HB_S + kk * 32 + quad * 8);
            const bf16x8 b_hi = *(const bf16x8*)(ec_hi + c * H_ + kk * 32 + quad * 8);
            const bf16x8 b_lo = *(const bf16x8*)(ec_lo + c * H_ + kk * 32 + quad * 8);
            acc = __builtin_amdgcn_mfma_f32_16x16x32_bf16(a_hi, b_hi, acc, 0, 0, 0);
            acc = __builtin_amdgcn_mfma_f32_16x16x32_bf16(a_lo, b_hi, acc, 0, 0, 0);
            acc = __builtin_amdgcn_mfma_f32_16x16x32_bf16(a_hi, b_lo, acc, 0, 0, 0);
        }
        #pragma unroll
        for (int r = 0; r < 4; ++r) sm[(quad * 4 + r) * C_ + c] = acc[r];
    }
    __syncthreads();

    // ---- phase D: coeffs + softmax (fp32) -> m_bf ----
    if (t < P_) {
        const int g = t >> 3;
        float S1 = 0.f, S2 = 0.f;
        #pragma unroll
        for (int q = 0; q < 8; ++q) { S1 += s1_s[g * 8 + q]; S2 += s2_s[g * 8 + q]; }
        const float invN = 1.f / (float)((P_ / G_) * C_ * H_);
        const float mu = S1 * invN;
        const float var = S2 * invN - mu * mu;
        const float rs = rsqrtf(var + EPS);
        const float a = rs * gn_w[t];
        const float ew = expand_w[t];
        cA[t] = a * fabsf(ew);             // coeff on TR = sum_c m*relu(x)
        cB[t] = a * fminf(ew, 0.f) + 1.f;  // coeff on U = sum_c m*x (+1 residual)
        cD[t] = gn_b[t] - mu * a;          // constant (sum_c m == 1)
    }
    {
        const int p = t >> 4, j = t & 15;
        float v0 = sm[p * C_ + j],      v1 = sm[p * C_ + j + 16];
        float v2 = sm[p * C_ + j + 32], v3 = sm[p * C_ + j + 48];
        float mx = fmaxf(fmaxf(v0, v1), fmaxf(v2, v3));
        #pragma unroll
        for (int m = 1; m < 16; m <<= 1) mx = fmaxf(mx, __shfl_xor(mx, m, 64));
        const float e0 = __expf(v0 - mx), e1 = __expf(v1 - mx);
        const float e2 = __expf(v2 - mx), e3 = __expf(v3 - mx);
        float ssum = (e0 + e1) + (e2 + e3);
        #pragma unroll
        for (int m = 1; m < 16; m <<= 1) ssum += __shfl_xor(ssum, m, 64);
        const float inv = 1.f / ssum;
        m_bf[p * MB_S + j]      = f2bf(e0 * inv);
        m_bf[p * MB_S + j + 16] = f2bf(e1 * inv);
        m_bf[p * MB_S + j + 32] = f2bf(e2 * inv);
        m_bf[p * MB_S + j + 48] = f2bf(e3 * inv);
    }
    __syncthreads();

    // ---- phase E (MFMA): U = m@x, TR = m@relu(x); out = cA*TR + cB*U + cD ----
    {
        f32x4 aU[2] = {{0.f,0.f,0.f,0.f},{0.f,0.f,0.f,0.f}};
        f32x4 aT[2] = {{0.f,0.f,0.f,0.f},{0.f,0.f,0.f,0.f}};
        #pragma unroll
        for (int kk = 0; kk < 2; ++kk) {
            const bf16x8 af = *(const bf16x8*)(m_bf + nl * MB_S + kk * 32 + quad * 8);
            #pragma unroll
            for (int T = 0; T < 2; ++T) {
                const int h = w * 32 + T * 16 + nl;
                // B-frag: x[c][h] for c = kk*32 + quad*8 + j (column read, 2-way banks)
                union { bf16x8 v; unsigned short s[8]; } bu;
                const int c0 = kk * 32 + quad * 8;
                #pragma unroll
                for (int j = 0; j < 8; ++j) bu.s[j] = xs_bf[(c0 + j) * XS_S + h];
                aU[T] = __builtin_amdgcn_mfma_f32_16x16x32_bf16(af, bu.v, aU[T], 0, 0, 0);
                const bf16x8 br = relu8(bu.v);
                aT[T] = __builtin_amdgcn_mfma_f32_16x16x32_bf16(af, br, aT[T], 0, 0, 0);
            }
        }
        float* ob = out + (size_t)b * (P_ * H_);
        #pragma unroll
        for (int T = 0; T < 2; ++T) {
            const int h = w * 32 + T * 16 + nl;
            #pragma unroll
            for (int r = 0; r < 4; ++r) {
                const int p = quad * 4 + r;
                ob[p * H_ + h] = cA[p] * aT[T][r] + cB[p] * aU[T][r] + cD[p];
            }
        }
    }
}

extern "C" void kernel_launch(void* const* d_in, const int* in_sizes, int n_in,
                              void* d_out, int out_size, void* d_ws, size_t ws_size,
                              hipStream_t stream) {
    const float* x          = (const float*)d_in[0];
    const float* x_prompt   = (const float*)d_in[1];
    const float* emb_column = (const float*)d_in[2];
    const float* emb_prompt = (const float*)d_in[3];
    const float* lin_w      = (const float*)d_in[4];
    const float* lin_b      = (const float*)d_in[5];
    const float* ln_col_w   = (const float*)d_in[6];
    const float* ln_col_b   = (const float*)d_in[7];
    const float* ln_pr_w    = (const float*)d_in[8];
    const float* ln_pr_b    = (const float*)d_in[9];
    const float* expand_w   = (const float*)d_in[10];
    const float* gn_w       = (const float*)d_in[11];
    const float* gn_b       = (const float*)d_in[12];
    float* out = (float*)d_out;

    float* hat0 = (float*)d_ws;                                 // [P,H] fp32
    unsigned short* ec_hi = (unsigned short*)(hat0 + P_ * H_);  // [C,H]
    unsigned short* ec_lo = ec_hi + C_ * H_;                    // [C,H]
    unsigned short* w2_hi = ec_lo + C_ * H_;                    // [H,H]
    unsigned short* w2_lo = w2_hi + H_ * H_;                    // [H,H]
    unsigned* flags = (unsigned*)(w2_lo + H_ * H_);             // [64]

    fused_kernel<<<B_, 256, 0, stream>>>(x, x_prompt, emb_column, emb_prompt,
                                         lin_w, lin_b, ln_col_w, ln_col_b,
                                         ln_pr_w, ln_pr_b, expand_w, gn_w, gn_b,
                                         hat0, ec_hi, ec_lo, w2_hi, w2_lo, flags, out);
}

// Round 3
// 106.170 us; speedup vs baseline: 1.6728x; 1.6728x over previous
//
#include <hip/hip_runtime.h>

#define B_ 512
#define C_ 64
#define H_ 128
#define P_ 16
#define G_ 2
#define EPS 1e-5f

// LDS row strides (bf16 units) chosen for bank behavior + 16B frag alignment
#define XS_S 130   // xs_bf [C][XS_S]: bank (c + h/2)%32 -> 2-way on column reads
#define HB_S 136   // xp/hat [P][HB_S]: 272B rows, 16B-aligned frags
#define MB_S 72    // m_bf [P][MB_S]

#define MAGIC 0x9E3779B1u

typedef __attribute__((ext_vector_type(8))) short bf16x8;
typedef __attribute__((ext_vector_type(4))) float f32x4;

__device__ __forceinline__ unsigned short f2bf(float f) {  // round-nearest-even
    union { float f; unsigned u; } v; v.f = f;
    return (unsigned short)((v.u + 0x7FFFu + ((v.u >> 16) & 1u)) >> 16);
}
__device__ __forceinline__ float bf2f(unsigned short h) {
    union { unsigned u; float f; } v; v.u = ((unsigned)h) << 16; return v.f;
}
// cheap round (ties-away) for the phase-E-only x staging: 2 ops per value
__device__ __forceinline__ unsigned packbf_fast(float lo, float hi) {
    union { float f; unsigned u; } a, b; a.f = lo; b.f = hi;
    return ((a.u + 0x8000u) >> 16) | (((b.u + 0x8000u) >> 16) << 16);
}
// split two floats into packed hi-pair and lo-pair (double-bf16, RNE)
__device__ __forceinline__ void split2(float a, float b, unsigned& hi, unsigned& lo) {
    const unsigned short ah = f2bf(a), bh = f2bf(b);
    const unsigned short al = f2bf(a - bf2f(ah)), bl = f2bf(b - bf2f(bh));
    hi = (unsigned)ah | ((unsigned)bh << 16);
    lo = (unsigned)al | ((unsigned)bl << 16);
}
// relu on 8 packed bf16: zero each half whose sign bit is set
__device__ __forceinline__ bf16x8 relu8(bf16x8 x) {
    union { bf16x8 v; unsigned u[4]; } a; a.v = x;
    #pragma unroll
    for (int i = 0; i < 4; ++i) {
        unsigned s = a.u[i] & 0x80008000u;
        a.u[i] &= ~((s >> 15) * 0xFFFFu);
    }
    return a.v;
}

// Single fused kernel. grid=512 == guaranteed capacity (2 blocks/CU * 256 CU via
// __launch_bounds__(256,2), LDS 40.8KB <= 80KB) -> all blocks co-resident, so the
// flag handshake below cannot deadlock regardless of dispatch order.
__global__ __launch_bounds__(256, 2) void fused_kernel(
    const float* __restrict__ x,          // [B,C,H]
    const float* __restrict__ x_prompt,   // [B,P,H]
    const float* __restrict__ emb_column, // [C,H]
    const float* __restrict__ emb_prompt, // [P,H]
    const float* __restrict__ lin_w,      // [H,2H]
    const float* __restrict__ lin_b,      // [H]
    const float* __restrict__ ln_col_w, const float* __restrict__ ln_col_b,
    const float* __restrict__ ln_pr_w,  const float* __restrict__ ln_pr_b,
    const float* __restrict__ expand_w,   // [P]
    const float* __restrict__ gn_w, const float* __restrict__ gn_b,  // [P]
    float* __restrict__ hat0,             // ws: [P,H] = ep@W1^T + lin_b + ep
    unsigned short* __restrict__ ec_hi,   // ws: [C,H]
    unsigned short* __restrict__ ec_lo,   // ws: [C,H]
    unsigned short* __restrict__ w2_hi,   // ws: [H,H], [h][k]=lin_w[h][H+k]
    unsigned short* __restrict__ w2_lo,   // ws: [H,H]
    unsigned* __restrict__ flags,         // ws: [64] writer-ready flags
    float* __restrict__ out)              // [B,P,H]
{
    __shared__ __align__(16) unsigned short xs_bf[C_ * XS_S];    // 16640 B
    __shared__ __align__(16) unsigned short xp_hi[P_ * HB_S];    // 4352 B
    __shared__ __align__(16) unsigned short xp_lo[P_ * HB_S];    // 4352 B
    __shared__ __align__(16) unsigned short hat_hi[P_ * HB_S];   // 4352 B
    __shared__ __align__(16) unsigned short hat_lo[P_ * HB_S];   // 4352 B
    __shared__ __align__(16) float sm[P_ * C_];                  // 4096 B (doubles as ep_row for writer blocks 48..63)
    __shared__ __align__(16) unsigned short m_bf[P_ * MB_S];     // 2304 B
    __shared__ float red[16];
    __shared__ float stat[4];   // Xsum, Xsq, R1=sum relu(x), R2=sum relu(x)^2
    __shared__ float s1_s[P_], s2_s[P_];
    __shared__ float cA[P_], cB[P_], cD[P_];

    const int t = threadIdx.x;
    const int b = blockIdx.x;
    const int lane = t & 63;
    const int w = t >> 6;       // wave id 0..3
    const int nl = lane & 15;   // MFMA n/m lane coord
    const int quad = lane >> 4; // MFMA quad

    // prefetch phase-B epilogue xp operand (latency overlaps staging/prep)
    float xpr[2][4];
    {
        const float* xpg = x_prompt + (size_t)b * (P_ * H_);
        #pragma unroll
        for (int T = 0; T < 2; ++T) {
            const int h = w * 32 + T * 16 + nl;
            #pragma unroll
            for (int r = 0; r < 4; ++r)
                xpr[T][r] = xpg[(quad * 4 + r) * H_ + h];
        }
    }

    // ---- distributed prep: first 64 blocks do a slice, then release a flag ----
    if (b < 64) {
        if (b < 32) {
            // w2 hi/lo split: 512 elements per block, 2 per thread
            const int f = b * 512 + t * 2;
            const int h = f >> 7, k = f & 127;
            const float2 q = *(const float2*)(lin_w + h * (2 * H_) + H_ + k);
            unsigned hi, lo;
            split2(q.x, q.y, hi, lo);
            *(unsigned*)(w2_hi + f) = hi;
            *(unsigned*)(w2_lo + f) = lo;
        } else if (b < 48) {
            // ec layernorm -> hi/lo: one row per wave
            const int r = (b - 32) * 4 + w;
            const float v0 = emb_column[r * H_ + lane];
            const float v1 = emb_column[r * H_ + lane + 64];
            float s = v0 + v1, s2 = v0 * v0 + v1 * v1;
            #pragma unroll
            for (int m = 1; m < 64; m <<= 1) { s += __shfl_xor(s, m, 64); s2 += __shfl_xor(s2, m, 64); }
            const float mean = s * (1.f / H_);
            const float rs = rsqrtf(s2 * (1.f / H_) - mean * mean + EPS);
            const float a0 = (v0 - mean) * rs * ln_col_w[lane]      + ln_col_b[lane];
            const float a1 = (v1 - mean) * rs * ln_col_w[lane + 64] + ln_col_b[lane + 64];
            const unsigned short h0 = f2bf(a0), h1 = f2bf(a1);
            ec_hi[r * H_ + lane]      = h0;
            ec_hi[r * H_ + lane + 64] = h1;
            ec_lo[r * H_ + lane]      = f2bf(a0 - bf2f(h0));
            ec_lo[r * H_ + lane + 64] = f2bf(a1 - bf2f(h1));
        } else {
            // ep layernorm (row p) + hat0 row p = ep@W1^T + lin_b + ep
            float* ep_row = sm;  // reuse sm (untouched until phase C)
            const int p = b - 48;
            const float v0 = emb_prompt[p * H_ + lane];
            const float v1 = emb_prompt[p * H_ + lane + 64];
            float s = v0 + v1, s2 = v0 * v0 + v1 * v1;
            #pragma unroll
            for (int m = 1; m < 64; m <<= 1) { s += __shfl_xor(s, m, 64); s2 += __shfl_xor(s2, m, 64); }
            const float mean = s * (1.f / H_);
            const float rs = rsqrtf(s2 * (1.f / H_) - mean * mean + EPS);
            if (w == 0) {
                ep_row[lane]      = (v0 - mean) * rs * ln_pr_w[lane]      + ln_pr_b[lane];
                ep_row[lane + 64] = (v1 - mean) * rs * ln_pr_w[lane + 64] + ln_pr_b[lane + 64];
            }
            __syncthreads();
            const int h = t >> 1;
            const int kh = (t & 1) * 16;  // float4 units
            const float4* w1 = (const float4*)(lin_w + h * (2 * H_)) + kh;
            const float4* e4 = (const float4*)ep_row + kh;
            float acc = 0.f;
            #pragma unroll
            for (int k = 0; k < 16; ++k) {
                const float4 W = w1[k], E = e4[k];
                acc += E.x * W.x + E.y * W.y + E.z * W.z + E.w * W.w;
            }
            acc += __shfl_xor(acc, 1, 64);
            if ((t & 1) == 0) hat0[p * H_ + h] = acc + lin_b[h] + ep_row[h];
        }
        // all block stores drained (syncthreads waits vmcnt(0)), then release flag
        __syncthreads();
        if (t == 0)
            __hip_atomic_store(&flags[b], MAGIC, __ATOMIC_RELEASE, __HIP_MEMORY_SCOPE_AGENT);
    }

    // ---- phase A: x[b] -> bf16 LDS + stats; x_prompt[b] -> hi/lo LDS ----
    {
        const float4* x4 = (const float4*)(x + (size_t)b * (C_ * H_));
        float xsum = 0.f, xsq = 0.f, r1 = 0.f, r2 = 0.f;
        #pragma unroll
        for (int i = 0; i < 8; ++i) {
            const int idx = t + 256 * i;
            const float4 v = x4[idx];
            const int c = idx >> 5;
            const int h0 = (idx & 31) * 4;
            unsigned* dst = (unsigned*)(xs_bf + c * XS_S + h0);
            dst[0] = packbf_fast(v.x, v.y);
            dst[1] = packbf_fast(v.z, v.w);
            xsum += (v.x + v.y) + (v.z + v.w);
            xsq  += (v.x * v.x + v.y * v.y) + (v.z * v.z + v.w * v.w);
            const float rx = fmaxf(v.x, 0.f), ry = fmaxf(v.y, 0.f);
            const float rz = fmaxf(v.z, 0.f), rw = fmaxf(v.w, 0.f);
            r1 += (rx + ry) + (rz + rw);
            r2 += (rx * rx + ry * ry) + (rz * rz + rw * rw);
        }
        #pragma unroll
        for (int m = 1; m < 64; m <<= 1) {
            xsum += __shfl_xor(xsum, m, 64);
            xsq  += __shfl_xor(xsq,  m, 64);
            r1   += __shfl_xor(r1,   m, 64);
            r2   += __shfl_xor(r2,   m, 64);
        }
        if (lane == 0) {
            red[w * 4 + 0] = xsum; red[w * 4 + 1] = xsq;
            red[w * 4 + 2] = r1;   red[w * 4 + 3] = r2;
        }
        // xp -> hi/lo LDS: 8 consecutive values per thread
        const float4* xp4 = (const float4*)(x_prompt + (size_t)b * (P_ * H_));
        const float4 a0 = xp4[2 * t], a1 = xp4[2 * t + 1];
        const int p = t >> 4, hh = (t & 15) * 8;
        uint4 ph, pl;
        split2(a0.x, a0.y, ph.x, pl.x);
        split2(a0.z, a0.w, ph.y, pl.y);
        split2(a1.x, a1.y, ph.z, pl.z);
        split2(a1.z, a1.w, ph.w, pl.w);
        *(uint4*)(xp_hi + p * HB_S + hh) = ph;
        *(uint4*)(xp_lo + p * HB_S + hh) = pl;
    }
    __syncthreads();
    if (t < 4) stat[t] = red[t] + red[4 + t] + red[8 + t] + red[12 + t];

    // ---- wait for prep writers. Wave 0 polls with RELAXED loads (no per-iter
    //      cache invalidate!), hoisted single ACQUIRE fence on exit, then the
    //      block barrier publishes visibility to the other waves. ----
    if (w == 0) {
        while (true) {
            const unsigned v = __hip_atomic_load(&flags[lane], __ATOMIC_RELAXED,
                                                 __HIP_MEMORY_SCOPE_AGENT);
            if (__ballot(v == MAGIC) == 0xFFFFFFFFFFFFFFFFull) break;
            __builtin_amdgcn_s_sleep(16);
        }
        __builtin_amdgcn_fence(__ATOMIC_ACQUIRE, "agent");
    }
    __syncthreads();

    // ---- phase B (MFMA, hi/lo): hat = xp@W2^T + hat0 + xp ; store hi/lo ----
    {
        // hat0 loads issued first; latency hides under LDS reads + MFMA below
        float h0r[2][4];
        #pragma unroll
        for (int T = 0; T < 2; ++T) {
            const int h = w * 32 + T * 16 + nl;
            #pragma unroll
            for (int r = 0; r < 4; ++r)
                h0r[T][r] = hat0[(quad * 4 + r) * H_ + h];
        }
        f32x4 acc[2] = {{0.f,0.f,0.f,0.f},{0.f,0.f,0.f,0.f}};
        #pragma unroll
        for (int kk = 0; kk < 4; ++kk) {
            const bf16x8 a_hi = *(const bf16x8*)(xp_hi + nl * HB_S + kk * 32 + quad * 8);
            const bf16x8 a_lo = *(const bf16x8*)(xp_lo + nl * HB_S + kk * 32 + quad * 8);
            #pragma unroll
            for (int T = 0; T < 2; ++T) {
                const int h = w * 32 + T * 16 + nl;
                const bf16x8 b_hi = *(const bf16x8*)(w2_hi + h * H_ + kk * 32 + quad * 8);
                const bf16x8 b_lo = *(const bf16x8*)(w2_lo + h * H_ + kk * 32 + quad * 8);
                acc[T] = __builtin_amdgcn_mfma_f32_16x16x32_bf16(a_hi, b_hi, acc[T], 0, 0, 0);
                acc[T] = __builtin_amdgcn_mfma_f32_16x16x32_bf16(a_lo, b_hi, acc[T], 0, 0, 0);
                acc[T] = __builtin_amdgcn_mfma_f32_16x16x32_bf16(a_hi, b_lo, acc[T], 0, 0, 0);
            }
        }
        #pragma unroll
        for (int T = 0; T < 2; ++T) {
            const int h = w * 32 + T * 16 + nl;
            #pragma unroll
            for (int r = 0; r < 4; ++r) {
                const int p = quad * 4 + r;
                const float val = acc[T][r] + h0r[T][r] + xpr[T][r];
                const unsigned short hi = f2bf(val);
                hat_hi[p * HB_S + h] = hi;
                hat_lo[p * HB_S + h] = f2bf(val - bf2f(hi));
            }
        }
    }
    __syncthreads();

    // ---- group-norm per-p partial sums (uses stat) ----
    if (t < P_) {
        const float ew = expand_w[t];
        const float Ap = fabsf(ew);
        const float Bp = fminf(ew, 0.f);
        s1_s[t] = Ap * stat[2] + Bp * stat[0];
        s2_s[t] = ew * ew * (ew >= 0.f ? stat[3] : (stat[1] - stat[3]));
    }
    // ---- phase C (MFMA, hi/lo): scores[p][c] = hat @ ec^T ----
    {
        f32x4 acc = {0.f, 0.f, 0.f, 0.f};
        const int c = w * 16 + nl;
        #pragma unroll
        for (int kk = 0; kk < 4; ++kk) {
            const bf16x8 a_hi = *(const bf16x8*)(hat_hi + nl * HB_S + kk * 32 + quad * 8);
            const bf16x8 a_lo = *(const bf16x8*)(hat_lo + nl * HB_S + kk * 32 + quad * 8);
            const bf16x8 b_hi = *(const bf16x8*)(ec_hi + c * H_ + kk * 32 + quad * 8);
            const bf16x8 b_lo = *(const bf16x8*)(ec_lo + c * H_ + kk * 32 + quad * 8);
            acc = __builtin_amdgcn_mfma_f32_16x16x32_bf16(a_hi, b_hi, acc, 0, 0, 0);
            acc = __builtin_amdgcn_mfma_f32_16x16x32_bf16(a_lo, b_hi, acc, 0, 0, 0);
            acc = __builtin_amdgcn_mfma_f32_16x16x32_bf16(a_hi, b_lo, acc, 0, 0, 0);
        }
        #pragma unroll
        for (int r = 0; r < 4; ++r) sm[(quad * 4 + r) * C_ + c] = acc[r];
    }
    __syncthreads();

    // ---- phase D: coeffs + softmax (fp32) -> m_bf ----
    if (t < P_) {
        const int g = t >> 3;
        float S1 = 0.f, S2 = 0.f;
        #pragma unroll
        for (int q = 0; q < 8; ++q) { S1 += s1_s[g * 8 + q]; S2 += s2_s[g * 8 + q]; }
        const float invN = 1.f / (float)((P_ / G_) * C_ * H_);
        const float mu = S1 * invN;
        const float var = S2 * invN - mu * mu;
        const float rs = rsqrtf(var + EPS);
        const float a = rs * gn_w[t];
        const float ew = expand_w[t];
        cA[t] = a * fabsf(ew);             // coeff on TR = sum_c m*relu(x)
        cB[t] = a * fminf(ew, 0.f) + 1.f;  // coeff on U = sum_c m*x (+1 residual)
        cD[t] = gn_b[t] - mu * a;          // constant (sum_c m == 1)
    }
    {
        const int p = t >> 4, j = t & 15;
        float v0 = sm[p * C_ + j],      v1 = sm[p * C_ + j + 16];
        float v2 = sm[p * C_ + j + 32], v3 = sm[p * C_ + j + 48];
        float mx = fmaxf(fmaxf(v0, v1), fmaxf(v2, v3));
        #pragma unroll
        for (int m = 1; m < 16; m <<= 1) mx = fmaxf(mx, __shfl_xor(mx, m, 64));
        const float e0 = __expf(v0 - mx), e1 = __expf(v1 - mx);
        const float e2 = __expf(v2 - mx), e3 = __expf(v3 - mx);
        float ssum = (e0 + e1) + (e2 + e3);
        #pragma unroll
        for (int m = 1; m < 16; m <<= 1) ssum += __shfl_xor(ssum, m, 64);
        const float inv = 1.f / ssum;
        m_bf[p * MB_S + j]      = f2bf(e0 * inv);
        m_bf[p * MB_S + j + 16] = f2bf(e1 * inv);
        m_bf[p * MB_S + j + 32] = f2bf(e2 * inv);
        m_bf[p * MB_S + j + 48] = f2bf(e3 * inv);
    }
    __syncthreads();

    // ---- phase E (MFMA): U = m@x, TR = m@relu(x); out = cA*TR + cB*U + cD ----
    {
        f32x4 aU[2] = {{0.f,0.f,0.f,0.f},{0.f,0.f,0.f,0.f}};
        f32x4 aT[2] = {{0.f,0.f,0.f,0.f},{0.f,0.f,0.f,0.f}};
        #pragma unroll
        for (int kk = 0; kk < 2; ++kk) {
            const bf16x8 af = *(const bf16x8*)(m_bf + nl * MB_S + kk * 32 + quad * 8);
            #pragma unroll
            for (int T = 0; T < 2; ++T) {
                const int h = w * 32 + T * 16 + nl;
                // B-frag: x[c][h] for c = kk*32 + quad*8 + j (column read, 2-way banks)
                union { bf16x8 v; unsigned short s[8]; } bu;
                const int c0 = kk * 32 + quad * 8;
                #pragma unroll
                for (int j = 0; j < 8; ++j) bu.s[j] = xs_bf[(c0 + j) * XS_S + h];
                aU[T] = __builtin_amdgcn_mfma_f32_16x16x32_bf16(af, bu.v, aU[T], 0, 0, 0);
                const bf16x8 br = relu8(bu.v);
                aT[T] = __builtin_amdgcn_mfma_f32_16x16x32_bf16(af, br, aT[T], 0, 0, 0);
            }
        }
        float* ob = out + (size_t)b * (P_ * H_);
        #pragma unroll
        for (int T = 0; T < 2; ++T) {
            const int h = w * 32 + T * 16 + nl;
            #pragma unroll
            for (int r = 0; r < 4; ++r) {
                const int p = quad * 4 + r;
                ob[p * H_ + h] = cA[p] * aT[T][r] + cB[p] * aU[T][r] + cD[p];
            }
        }
    }
}

extern "C" void kernel_launch(void* const* d_in, const int* in_sizes, int n_in,
                              void* d_out, int out_size, void* d_ws, size_t ws_size,
                              hipStream_t stream) {
    const float* x          = (const float*)d_in[0];
    const float* x_prompt   = (const float*)d_in[1];
    const float* emb_column = (const float*)d_in[2];
    const float* emb_prompt = (const float*)d_in[3];
    const float* lin_w      = (const float*)d_in[4];
    const float* lin_b      = (const float*)d_in[5];
    const float* ln_col_w   = (const float*)d_in[6];
    const float* ln_col_b   = (const float*)d_in[7];
    const float* ln_pr_w    = (const float*)d_in[8];
    const float* ln_pr_b    = (const float*)d_in[9];
    const float* expand_w   = (const float*)d_in[10];
    const float* gn_w       = (const float*)d_in[11];
    const float* gn_b       = (const float*)d_in[12];
    float* out = (float*)d_out;

    float* hat0 = (float*)d_ws;                                 // [P,H] fp32
    unsigned short* ec_hi = (unsigned short*)(hat0 + P_ * H_);  // [C,H]
    unsigned short* ec_lo = ec_hi + C_ * H_;                    // [C,H]
    unsigned short* w2_hi = ec_lo + C_ * H_;                    // [H,H]
    unsigned short* w2_lo = w2_hi + H_ * H_;                    // [H,H]
    unsigned* flags = (unsigned*)(w2_lo + H_ * H_);             // [64]

    fused_kernel<<<B_, 256, 0, stream>>>(x, x_prompt, emb_column, emb_prompt,
                                         lin_w, lin_b, ln_col_w, ln_col_b,
                                         ln_pr_w, ln_pr_b, expand_w, gn_w, gn_b,
                                         hat0, ec_hi, ec_lo, w2_hi, w2_lo, flags, out);
}

// Round 6
// 98.884 us; speedup vs baseline: 1.7961x; 1.0737x over previous
//
#include <hip/hip_runtime.h>

#define B_ 512
#define C_ 64
#define H_ 128
#define P_ 16
#define G_ 2
#define EPS 1e-5f

// LDS row strides (bf16 units) chosen for bank behavior + 16B frag alignment
#define XS_S 130   // xs_bf [C][XS_S]: bank (c + h/2)%32 -> 2-way on column reads
#define HB_S 136   // xp/hat [P][HB_S]: 272B rows, 16B-aligned frags
#define MB_S 72    // m_bf [P][MB_S]

typedef __attribute__((ext_vector_type(8))) short bf16x8;
typedef __attribute__((ext_vector_type(4))) float f32x4;

__device__ __forceinline__ unsigned short f2bf(float f) {  // round-nearest-even
    union { float f; unsigned u; } v; v.f = f;
    return (unsigned short)((v.u + 0x7FFFu + ((v.u >> 16) & 1u)) >> 16);
}
__device__ __forceinline__ float bf2f(unsigned short h) {
    union { unsigned u; float f; } v; v.u = ((unsigned)h) << 16; return v.f;
}
// cheap round (ties-away) for the phase-E-only x staging: 2 ops per value
__device__ __forceinline__ unsigned packbf_fast(float lo, float hi) {
    union { float f; unsigned u; } a, b; a.f = lo; b.f = hi;
    return ((a.u + 0x8000u) >> 16) | (((b.u + 0x8000u) >> 16) << 16);
}
// split two floats into packed hi-pair and lo-pair (double-bf16, RNE)
__device__ __forceinline__ void split2(float a, float b, unsigned& hi, unsigned& lo) {
    const unsigned short ah = f2bf(a), bh = f2bf(b);
    const unsigned short al = f2bf(a - bf2f(ah)), bl = f2bf(b - bf2f(bh));
    hi = (unsigned)ah | ((unsigned)bh << 16);
    lo = (unsigned)al | ((unsigned)bl << 16);
}
// relu on 8 packed bf16: zero each half whose sign bit is set
__device__ __forceinline__ bf16x8 relu8(bf16x8 x) {
    union { bf16x8 v; unsigned u[4]; } a; a.v = x;
    #pragma unroll
    for (int i = 0; i < 4; ++i) {
        unsigned s = a.u[i] & 0x80008000u;
        a.u[i] &= ~((s >> 15) * 0xFFFFu);
    }
    return a.v;
}

// ---- kernel 1 (64 blocks): layernorms + hat0 + hi/lo weight prep, spread wide
__global__ __launch_bounds__(256) void prep_kernel(
    const float* __restrict__ emb_column,  // [C,H]
    const float* __restrict__ emb_prompt,  // [P,H]
    const float* __restrict__ lin_w,       // [H,2H]
    const float* __restrict__ lin_b,       // [H]
    const float* __restrict__ ln_col_w, const float* __restrict__ ln_col_b,
    const float* __restrict__ ln_pr_w,  const float* __restrict__ ln_pr_b,
    float* __restrict__ hat0,              // ws: [P,H] = ep@W1^T + lin_b + ep
    unsigned short* __restrict__ ec_hi,    // ws: [C,H]
    unsigned short* __restrict__ ec_lo,    // ws: [C,H]
    unsigned short* __restrict__ w2_hi,    // ws: [H,H], [h][k]=lin_w[h][H+k]
    unsigned short* __restrict__ w2_lo)    // ws: [H,H]
{
    __shared__ __align__(16) float ep_row[H_];
    const int t = threadIdx.x;
    const int blk = blockIdx.x;
    const int lane = t & 63;
    const int w = t >> 6;

    if (blk < 16) {
        // --- ep layernorm for row p=blk (wave 0), then hat0 row p ---
        const int p = blk;
        const float v0 = emb_prompt[p * H_ + lane];
        const float v1 = emb_prompt[p * H_ + lane + 64];
        float s = v0 + v1, s2 = v0 * v0 + v1 * v1;
        #pragma unroll
        for (int m = 1; m < 64; m <<= 1) { s += __shfl_xor(s, m, 64); s2 += __shfl_xor(s2, m, 64); }
        const float mean = s * (1.f / H_);
        const float rs = rsqrtf(s2 * (1.f / H_) - mean * mean + EPS);
        if (w == 0) {
            ep_row[lane]      = (v0 - mean) * rs * ln_pr_w[lane]      + ln_pr_b[lane];
            ep_row[lane + 64] = (v1 - mean) * rs * ln_pr_w[lane + 64] + ln_pr_b[lane + 64];
        }
        __syncthreads();
        // hat0[p][h]: 2 threads per h, each half of K
        const int h = t >> 1;
        const int kh = (t & 1) * 16;  // float4 units
        const float4* w1 = (const float4*)(lin_w + h * (2 * H_)) + kh;
        const float4* e4 = (const float4*)ep_row + kh;
        float acc = 0.f;
        #pragma unroll
        for (int k = 0; k < 16; ++k) {
            const float4 W = w1[k], E = e4[k];
            acc += E.x * W.x + E.y * W.y + E.z * W.z + E.w * W.w;
        }
        acc += __shfl_xor(acc, 1, 64);
        if ((t & 1) == 0) hat0[p * H_ + h] = acc + lin_b[h] + ep_row[h];
    } else if (blk < 32) {
        // --- ec layernorm -> hi/lo: one row per wave ---
        const int r = (blk - 16) * 4 + w;
        const float v0 = emb_column[r * H_ + lane];
        const float v1 = emb_column[r * H_ + lane + 64];
        float s = v0 + v1, s2 = v0 * v0 + v1 * v1;
        #pragma unroll
        for (int m = 1; m < 64; m <<= 1) { s += __shfl_xor(s, m, 64); s2 += __shfl_xor(s2, m, 64); }
        const float mean = s * (1.f / H_);
        const float rs = rsqrtf(s2 * (1.f / H_) - mean * mean + EPS);
        const float a0 = (v0 - mean) * rs * ln_col_w[lane]      + ln_col_b[lane];
        const float a1 = (v1 - mean) * rs * ln_col_w[lane + 64] + ln_col_b[lane + 64];
        const unsigned short h0 = f2bf(a0), h1 = f2bf(a1);
        ec_hi[r * H_ + lane]      = h0;
        ec_hi[r * H_ + lane + 64] = h1;
        ec_lo[r * H_ + lane]      = f2bf(a0 - bf2f(h0));
        ec_lo[r * H_ + lane + 64] = f2bf(a1 - bf2f(h1));
    } else {
        // --- w2 hi/lo split: 512 elements per block, 2 per thread ---
        const int f = (blk - 32) * 512 + t * 2;
        const int h = f >> 7, k = f & 127;
        const float2 q = *(const float2*)(lin_w + h * (2 * H_) + H_ + k);
        unsigned hi, lo;
        split2(q.x, q.y, hi, lo);
        *(unsigned*)(w2_hi + f) = hi;
        *(unsigned*)(w2_lo + f) = lo;
    }
}

// ---------------- kernel 2: one block per batch element, MFMA + hi/lo --------
__global__ __launch_bounds__(256) void main_kernel(
    const float* __restrict__ x,         // [B,C,H]
    const float* __restrict__ x_prompt,  // [B,P,H]
    const float* __restrict__ expand_w,  // [P]
    const float* __restrict__ gn_w, const float* __restrict__ gn_b,  // [P]
    const float* __restrict__ hat0,             // [P,H] fp32
    const unsigned short* __restrict__ ec_hi,   // [C,H]
    const unsigned short* __restrict__ ec_lo,
    const unsigned short* __restrict__ w2_hi,   // [H,H]
    const unsigned short* __restrict__ w2_lo,
    float* __restrict__ out)             // [B,P,H]
{
    __shared__ __align__(16) unsigned short xs_bf[C_ * XS_S];    // 16640 B
    __shared__ __align__(16) unsigned short xp_hi[P_ * HB_S];    // 4352 B
    __shared__ __align__(16) unsigned short xp_lo[P_ * HB_S];    // 4352 B
    __shared__ __align__(16) unsigned short hat_hi[P_ * HB_S];   // 4352 B
    __shared__ __align__(16) unsigned short hat_lo[P_ * HB_S];   // 4352 B
    __shared__ __align__(16) float sm[P_ * C_];                  // 4096 B
    __shared__ __align__(16) unsigned short m_bf[P_ * MB_S];     // 2304 B
    __shared__ float red[16];
    __shared__ float stat[4];   // Xsum, Xsq, R1=sum relu(x), R2=sum relu(x)^2
    __shared__ float s1_s[P_], s2_s[P_];
    __shared__ float cA[P_], cB[P_], cD[P_];

    const int t = threadIdx.x;
    const int b = blockIdx.x;
    const int lane = t & 63;
    const int w = t >> 6;       // wave id 0..3
    const int nl = lane & 15;   // MFMA n/m lane coord
    const int quad = lane >> 4; // MFMA quad

    // prefetch phase-B epilogue operands (latency overlaps phase-A staging)
    float h0r[2][4], xpr[2][4];
    {
        const float* xpg = x_prompt + (size_t)b * (P_ * H_);
        #pragma unroll
        for (int T = 0; T < 2; ++T) {
            const int h = w * 32 + T * 16 + nl;
            #pragma unroll
            for (int r = 0; r < 4; ++r) {
                const int p = quad * 4 + r;
                h0r[T][r] = hat0[p * H_ + h];
                xpr[T][r] = xpg[p * H_ + h];
            }
        }
    }

    // ---- phase A: x[b] -> bf16 LDS + stats; x_prompt[b] -> hi/lo LDS ----
    {
        const float4* x4 = (const float4*)(x + (size_t)b * (C_ * H_));
        float xsum = 0.f, xsq = 0.f, r1 = 0.f, r2 = 0.f;
        #pragma unroll
        for (int i = 0; i < 8; ++i) {
            const int idx = t + 256 * i;
            const float4 v = x4[idx];
            const int c = idx >> 5;
            const int h0 = (idx & 31) * 4;
            unsigned* dst = (unsigned*)(xs_bf + c * XS_S + h0);
            dst[0] = packbf_fast(v.x, v.y);
            dst[1] = packbf_fast(v.z, v.w);
            xsum += (v.x + v.y) + (v.z + v.w);
            xsq  += (v.x * v.x + v.y * v.y) + (v.z * v.z + v.w * v.w);
            const float rx = fmaxf(v.x, 0.f), ry = fmaxf(v.y, 0.f);
            const float rz = fmaxf(v.z, 0.f), rw = fmaxf(v.w, 0.f);
            r1 += (rx + ry) + (rz + rw);
            r2 += (rx * rx + ry * ry) + (rz * rz + rw * rw);
        }
        #pragma unroll
        for (int m = 1; m < 64; m <<= 1) {
            xsum += __shfl_xor(xsum, m, 64);
            xsq  += __shfl_xor(xsq,  m, 64);
            r1   += __shfl_xor(r1,   m, 64);
            r2   += __shfl_xor(r2,   m, 64);
        }
        if (lane == 0) {
            red[w * 4 + 0] = xsum; red[w * 4 + 1] = xsq;
            red[w * 4 + 2] = r1;   red[w * 4 + 3] = r2;
        }
        // xp -> hi/lo LDS: 8 consecutive values per thread
        const float4* xp4 = (const float4*)(x_prompt + (size_t)b * (P_ * H_));
        const float4 a0 = xp4[2 * t], a1 = xp4[2 * t + 1];
        const int p = t >> 4, hh = (t & 15) * 8;
        uint4 ph, pl;
        split2(a0.x, a0.y, ph.x, pl.x);
        split2(a0.z, a0.w, ph.y, pl.y);
        split2(a1.x, a1.y, ph.z, pl.z);
        split2(a1.z, a1.w, ph.w, pl.w);
        *(uint4*)(xp_hi + p * HB_S + hh) = ph;
        *(uint4*)(xp_lo + p * HB_S + hh) = pl;
    }
    __syncthreads();
    if (t < 4) stat[t] = red[t] + red[4 + t] + red[8 + t] + red[12 + t];

    // ---- phase B (MFMA, hi/lo): hat = xp@W2^T + hat0 + xp ; store hi/lo ----
    {
        f32x4 acc[2] = {{0.f,0.f,0.f,0.f},{0.f,0.f,0.f,0.f}};
        #pragma unroll
        for (int kk = 0; kk < 4; ++kk) {
            const bf16x8 a_hi = *(const bf16x8*)(xp_hi + nl * HB_S + kk * 32 + quad * 8);
            const bf16x8 a_lo = *(const bf16x8*)(xp_lo + nl * HB_S + kk * 32 + quad * 8);
            #pragma unroll
            for (int T = 0; T < 2; ++T) {
                const int h = w * 32 + T * 16 + nl;
                const bf16x8 b_hi = *(const bf16x8*)(w2_hi + h * H_ + kk * 32 + quad * 8);
                const bf16x8 b_lo = *(const bf16x8*)(w2_lo + h * H_ + kk * 32 + quad * 8);
                acc[T] = __builtin_amdgcn_mfma_f32_16x16x32_bf16(a_hi, b_hi, acc[T], 0, 0, 0);
                acc[T] = __builtin_amdgcn_mfma_f32_16x16x32_bf16(a_lo, b_hi, acc[T], 0, 0, 0);
                acc[T] = __builtin_amdgcn_mfma_f32_16x16x32_bf16(a_hi, b_lo, acc[T], 0, 0, 0);
            }
        }
        #pragma unroll
        for (int T = 0; T < 2; ++T) {
            const int h = w * 32 + T * 16 + nl;
            #pragma unroll
            for (int r = 0; r < 4; ++r) {
                const int p = quad * 4 + r;
                const float val = acc[T][r] + h0r[T][r] + xpr[T][r];
                const unsigned short hi = f2bf(val);
                hat_hi[p * HB_S + h] = hi;
                hat_lo[p * HB_S + h] = f2bf(val - bf2f(hi));
            }
        }
    }
    __syncthreads();

    // ---- group-norm per-p partial sums (uses stat) ----
    if (t < P_) {
        const float ew = expand_w[t];
        const float Ap = fabsf(ew);
        const float Bp = fminf(ew, 0.f);
        s1_s[t] = Ap * stat[2] + Bp * stat[0];
        s2_s[t] = ew * ew * (ew >= 0.f ? stat[3] : (stat[1] - stat[3]));
    }
    // ---- phase C (MFMA, hi/lo): scores[p][c] = hat @ ec^T ----
    {
        f32x4 acc = {0.f, 0.f, 0.f, 0.f};
        const int c = w * 16 + nl;
        #pragma unroll
        for (int kk = 0; kk < 4; ++kk) {
            const bf16x8 a_hi = *(const bf16x8*)(hat_hi + nl * HB_S + kk * 32 + quad * 8);
            const bf16x8 a_lo = *(const bf16x8*)(hat_lo + nl * HB_S + kk * 32 + quad * 8);
            const bf16x8 b_hi = *(const bf16x8*)(ec_hi + c * H_ + kk * 32 + quad * 8);
            const bf16x8 b_lo = *(const bf16x8*)(ec_lo + c * H_ + kk * 32 + quad * 8);
            acc = __builtin_amdgcn_mfma_f32_16x16x32_bf16(a_hi, b_hi, acc, 0, 0, 0);
            acc = __builtin_amdgcn_mfma_f32_16x16x32_bf16(a_lo, b_hi, acc, 0, 0, 0);
            acc = __builtin_amdgcn_mfma_f32_16x16x32_bf16(a_hi, b_lo, acc, 0, 0, 0);
        }
        #pragma unroll
        for (int r = 0; r < 4; ++r) sm[(quad * 4 + r) * C_ + c] = acc[r];
    }
    __syncthreads();

    // ---- phase D: coeffs + softmax (fp32) -> m_bf ----
    if (t < P_) {
        const int g = t >> 3;
        float S1 = 0.f, S2 = 0.f;
        #pragma unroll
        for (int q = 0; q < 8; ++q) { S1 += s1_s[g * 8 + q]; S2 += s2_s[g * 8 + q]; }
        const float invN = 1.f / (float)((P_ / G_) * C_ * H_);
        const float mu = S1 * invN;
        const float var = S2 * invN - mu * mu;
        const float rs = rsqrtf(var + EPS);
        const float a = rs * gn_w[t];
        const float ew = expand_w[t];
        cA[t] = a * fabsf(ew);             // coeff on TR = sum_c m*relu(x)
        cB[t] = a * fminf(ew, 0.f) + 1.f;  // coeff on U = sum_c m*x (+1 residual)
        cD[t] = gn_b[t] - mu * a;          // constant (sum_c m == 1)
    }
    {
        const int p = t >> 4, j = t & 15;
        float v0 = sm[p * C_ + j],      v1 = sm[p * C_ + j + 16];
        float v2 = sm[p * C_ + j + 32], v3 = sm[p * C_ + j + 48];
        float mx = fmaxf(fmaxf(v0, v1), fmaxf(v2, v3));
        #pragma unroll
        for (int m = 1; m < 16; m <<= 1) mx = fmaxf(mx, __shfl_xor(mx, m, 64));
        const float e0 = __expf(v0 - mx), e1 = __expf(v1 - mx);
        const float e2 = __expf(v2 - mx), e3 = __expf(v3 - mx);
        float ssum = (e0 + e1) + (e2 + e3);
        #pragma unroll
        for (int m = 1; m < 16; m <<= 1) ssum += __shfl_xor(ssum, m, 64);
        const float inv = 1.f / ssum;
        m_bf[p * MB_S + j]      = f2bf(e0 * inv);
        m_bf[p * MB_S + j + 16] = f2bf(e1 * inv);
        m_bf[p * MB_S + j + 32] = f2bf(e2 * inv);
        m_bf[p * MB_S + j + 48] = f2bf(e3 * inv);
    }
    __syncthreads();

    // ---- phase E (MFMA): U = m@x, TR = m@relu(x); out = cA*TR + cB*U + cD ----
    {
        f32x4 aU[2] = {{0.f,0.f,0.f,0.f},{0.f,0.f,0.f,0.f}};
        f32x4 aT[2] = {{0.f,0.f,0.f,0.f},{0.f,0.f,0.f,0.f}};
        #pragma unroll
        for (int kk = 0; kk < 2; ++kk) {
            const bf16x8 af = *(const bf16x8*)(m_bf + nl * MB_S + kk * 32 + quad * 8);
            #pragma unroll
            for (int T = 0; T < 2; ++T) {
                const int h = w * 32 + T * 16 + nl;
                // B-frag: x[c][h] for c = kk*32 + quad*8 + j (column read, 2-way banks)
                union { bf16x8 v; unsigned short s[8]; } bu;
                const int c0 = kk * 32 + quad * 8;
                #pragma unroll
                for (int j = 0; j < 8; ++j) bu.s[j] = xs_bf[(c0 + j) * XS_S + h];
                aU[T] = __builtin_amdgcn_mfma_f32_16x16x32_bf16(af, bu.v, aU[T], 0, 0, 0);
                const bf16x8 br = relu8(bu.v);
                aT[T] = __builtin_amdgcn_mfma_f32_16x16x32_bf16(af, br, aT[T], 0, 0, 0);
            }
        }
        float* ob = out + (size_t)b * (P_ * H_);
        #pragma unroll
        for (int T = 0; T < 2; ++T) {
            const int h = w * 32 + T * 16 + nl;
            #pragma unroll
            for (int r = 0; r < 4; ++r) {
                const int p = quad * 4 + r;
                ob[p * H_ + h] = cA[p] * aT[T][r] + cB[p] * aU[T][r] + cD[p];
            }
        }
    }
}

extern "C" void kernel_launch(void* const* d_in, const int* in_sizes, int n_in,
                              void* d_out, int out_size, void* d_ws, size_t ws_size,
                              hipStream_t stream) {
    const float* x          = (const float*)d_in[0];
    const float* x_prompt   = (const float*)d_in[1];
    const float* emb_column = (const float*)d_in[2];
    const float* emb_prompt = (const float*)d_in[3];
    const float* lin_w      = (const float*)d_in[4];
    const float* lin_b      = (const float*)d_in[5];
    const float* ln_col_w   = (const float*)d_in[6];
    const float* ln_col_b   = (const float*)d_in[7];
    const float* ln_pr_w    = (const float*)d_in[8];
    const float* ln_pr_b    = (const float*)d_in[9];
    const float* expand_w   = (const float*)d_in[10];
    const float* gn_w       = (const float*)d_in[11];
    const float* gn_b       = (const float*)d_in[12];
    float* out = (float*)d_out;

    float* hat0 = (float*)d_ws;                                 // [P,H] fp32
    unsigned short* ec_hi = (unsigned short*)(hat0 + P_ * H_);  // [C,H]
    unsigned short* ec_lo = ec_hi + C_ * H_;                    // [C,H]
    unsigned short* w2_hi = ec_lo + C_ * H_;                    // [H,H]
    unsigned short* w2_lo = w2_hi + H_ * H_;                    // [H,H]

    prep_kernel<<<64, 256, 0, stream>>>(emb_column, emb_prompt, lin_w, lin_b,
                                        ln_col_w, ln_col_b, ln_pr_w, ln_pr_b,
                                        hat0, ec_hi, ec_lo, w2_hi, w2_lo);
    main_kernel<<<B_, 256, 0, stream>>>(x, x_prompt, expand_w, gn_w, gn_b,
                                        hat0, ec_hi, ec_lo, w2_hi, w2_lo, out);
}